// Round 1
// baseline (1421.389 us; speedup 1.0000x reference)
//
#include <hip/hip_runtime.h>
#include <hip/hip_bf16.h>

#define DD 768
#define NPATCH 576
#define BM 32            // memory rows staged per chunk
#define NKS 24           // 768 / 32
#define PT_PER_WAVE 9    // 36 patch tiles / 4 waves
#define EPSF 1e-6f
#define NBLK 2048

typedef short bf16x8 __attribute__((ext_vector_type(8)));
typedef float f32x4 __attribute__((ext_vector_type(4)));

__device__ __forceinline__ unsigned short f2bf(float x) {
  __hip_bfloat16 h = __float2bfloat16(x);
  return __builtin_bit_cast(unsigned short, h);
}

// ---------------- kernel 1: normalize patches -> bf16 F ----------------
__global__ __launch_bounds__(256) void k_patchnorm(const float* __restrict__ pf,
                                                   unsigned short* __restrict__ F) {
  int row = blockIdx.x;          // 576
  int t = threadIdx.x;           // 256
  const float* src = pf + row * DD;
  float v0 = src[t], v1 = src[t + 256], v2 = src[t + 512];
  float ss = v0 * v0 + v1 * v1 + v2 * v2;
#pragma unroll
  for (int m = 1; m < 64; m <<= 1) ss += __shfl_xor(ss, m, 64);
  __shared__ float wss[4];
  if ((t & 63) == 0) wss[t >> 6] = ss;
  __syncthreads();
  float tot = wss[0] + wss[1] + wss[2] + wss[3];
  float inv = 1.0f / (sqrtf(tot) + EPSF);
  unsigned short* dst = F + (size_t)row * DD;
  dst[t] = f2bf(v0 * inv);
  dst[t + 256] = f2bf(v1 * inv);
  dst[t + 512] = f2bf(v2 * inv);
}

// ---------------- kernel 2: main MFMA distance/min kernel ----------------
__global__ __launch_bounds__(256) void k_main(const unsigned short* __restrict__ F,
                                              const float* __restrict__ mem,
                                              float* __restrict__ partial,
                                              int M, int nchunk) {
  __shared__ __align__(16) unsigned char mtile[BM * DD * 2];  // 48 KiB bf16 tile
  __shared__ float ssq[BM];
  __shared__ float smin[NPATCH];

  int t = threadIdx.x;
  int w = t >> 6;          // wave 0..3
  int l = t & 63;
  int l15 = l & 15;
  int lhi = l >> 4;

  for (int p = t; p < NPATCH; p += 256) smin[p] = 1e30f;

  for (int chunk = blockIdx.x; chunk < nchunk; chunk += gridDim.x) {
    __syncthreads();  // previous iteration done with mtile/ssq; smin init visible
    // ---- stage: 32 rows x 768 fp32 -> bf16 LDS (swizzled), sumsq per row ----
    {
      int row = t >> 3;              // 0..31
      int part = t & 7;              // 0..7, 96 floats each
      int grow = chunk * BM + row;
      if (grow > M - 1) grow = M - 1;          // clamp (tail safety)
      const float4* src = (const float4*)(mem + (size_t)grow * DD + part * 96);
      char* rowb = (char*)mtile + row * 1536;
      int kb0 = part * 192;
      int sw = (row & 7) << 4;
      float ss = 0.f;
#pragma unroll
      for (int i = 0; i < 24; ++i) {
        float4 v = src[i];
        ss += v.x * v.x + v.y * v.y + v.z * v.z + v.w * v.w;
        unsigned int lo = (unsigned int)f2bf(v.x) | ((unsigned int)f2bf(v.y) << 16);
        unsigned int hi = (unsigned int)f2bf(v.z) | ((unsigned int)f2bf(v.w) << 16);
        uint2 u; u.x = lo; u.y = hi;
        *(uint2*)(rowb + ((kb0 + i * 8) ^ sw)) = u;
      }
      ss += __shfl_xor(ss, 1, 64);
      ss += __shfl_xor(ss, 2, 64);
      ss += __shfl_xor(ss, 4, 64);
      if (part == 0) ssq[row] = ss;
    }
    __syncthreads();

    // ---- MFMA: wave w covers patch tiles w*9..w*9+8, full 32 mem rows ----
    f32x4 acc[PT_PER_WAVE][2];
#pragma unroll
    for (int p = 0; p < PT_PER_WAVE; ++p) {
      f32x4 z = {0.f, 0.f, 0.f, 0.f};
      acc[p][0] = z;
      acc[p][1] = z;
    }
    const unsigned short* fb = F + (size_t)(w * PT_PER_WAVE * 16 + l15) * DD + lhi * 8;
    int sw = (l15 & 7) << 4;                       // same for rows l15 and 16+l15
    char* b0base = (char*)mtile + l15 * 1536;
    char* b1base = (char*)mtile + (16 + l15) * 1536;
#pragma unroll
    for (int ks = 0; ks < NKS; ++ks) {
      int kb = (ks * 64 + lhi * 16) ^ sw;
      bf16x8 b0 = *(const bf16x8*)(b0base + kb);
      bf16x8 b1 = *(const bf16x8*)(b1base + kb);
      const unsigned short* fk = fb + ks * 32;
#pragma unroll
      for (int p = 0; p < PT_PER_WAVE; ++p) {
        bf16x8 a = *(const bf16x8*)(fk + p * 16 * DD);
        acc[p][0] = __builtin_amdgcn_mfma_f32_16x16x32_bf16(a, b0, acc[p][0], 0, 0, 0);
        acc[p][1] = __builtin_amdgcn_mfma_f32_16x16x32_bf16(a, b1, acc[p][1], 0, 0, 0);
      }
    }

    // ---- epilogue: dist = 1 - dot/(||mem||+eps); min over 32 rows ----
    int mbase = chunk * BM;
    float inv0 = 1.0f / (sqrtf(ssq[l15]) + EPSF);
    float inv1 = 1.0f / (sqrtf(ssq[16 + l15]) + EPSF);
    bool ok0 = (mbase + l15) < M;
    bool ok1 = (mbase + 16 + l15) < M;
#pragma unroll
    for (int p = 0; p < PT_PER_WAVE; ++p) {
      float d[4];
#pragma unroll
      for (int r = 0; r < 4; ++r) {
        float e0 = ok0 ? (1.0f - acc[p][0][r] * inv0) : 1e30f;
        float e1 = ok1 ? (1.0f - acc[p][1][r] * inv1) : 1e30f;
        d[r] = fminf(e0, e1);
      }
#pragma unroll
      for (int mask = 1; mask <= 8; mask <<= 1) {
#pragma unroll
        for (int r = 0; r < 4; ++r) d[r] = fminf(d[r], __shfl_xor(d[r], mask, 64));
      }
      if (l15 == 0) {
        int pbase = (w * PT_PER_WAVE + p) * 16 + lhi * 4;
#pragma unroll
        for (int r = 0; r < 4; ++r) smin[pbase + r] = fminf(smin[pbase + r], d[r]);
      }
    }
  }
  __syncthreads();
  size_t ob = (size_t)blockIdx.x * NPATCH;
  for (int p = t; p < NPATCH; p += 256) partial[ob + p] = smin[p];
}

// ---------------- kernel 3: min over partials -> patch_scores ----------------
__global__ __launch_bounds__(256) void k_colmin(const float* __restrict__ partial,
                                                float* __restrict__ out, int nb) {
  int p = blockIdx.x;   // 576
  int t = threadIdx.x;
  float v = 1e30f;
  for (int b = t; b < nb; b += 256) v = fminf(v, partial[(size_t)b * NPATCH + p]);
#pragma unroll
  for (int m = 1; m < 64; m <<= 1) v = fminf(v, __shfl_xor(v, m, 64));
  __shared__ float wmin[4];
  if ((t & 63) == 0) wmin[t >> 6] = v;
  __syncthreads();
  if (t == 0) out[p] = fminf(fminf(wmin[0], wmin[1]), fminf(wmin[2], wmin[3]));
}

// ---------------- kernel 4: top-k mean -> image score ----------------
__global__ __launch_bounds__(256) void k_topk(float* __restrict__ out,
                                              const int* __restrict__ topk_p) {
  __shared__ float vals[NPATCH];
  __shared__ float wv[4];
  __shared__ int wi[4];
  __shared__ float ssum;
  int t = threadIdx.x;
  for (int p = t; p < NPATCH; p += 256) vals[p] = out[p];
  if (t == 0) ssum = 0.f;
  int k = topk_p[0];
  if (k > NPATCH) k = NPATCH;
  if (k < 1) k = 1;
  __syncthreads();
  for (int it = 0; it < k; ++it) {
    float bv = -1e30f;
    int bi = 0;
    for (int p = t; p < NPATCH; p += 256) {
      float x = vals[p];
      if (x > bv) { bv = x; bi = p; }
    }
#pragma unroll
    for (int m = 1; m < 64; m <<= 1) {
      float ov = __shfl_xor(bv, m, 64);
      int oi = __shfl_xor(bi, m, 64);
      if (ov > bv || (ov == bv && oi < bi)) { bv = ov; bi = oi; }
    }
    if ((t & 63) == 0) { wv[t >> 6] = bv; wi[t >> 6] = bi; }
    __syncthreads();
    if (t == 0) {
      float fbv = wv[0]; int fbi = wi[0];
      for (int q = 1; q < 4; ++q)
        if (wv[q] > fbv || (wv[q] == fbv && wi[q] < fbi)) { fbv = wv[q]; fbi = wi[q]; }
      ssum += fbv;
      vals[fbi] = -1e30f;
    }
    __syncthreads();
  }
  if (t == 0) out[NPATCH] = ssum / (float)k;
}

extern "C" void kernel_launch(void* const* d_in, const int* in_sizes, int n_in,
                              void* d_out, int out_size, void* d_ws, size_t ws_size,
                              hipStream_t stream) {
  const float* pf = (const float*)d_in[0];
  const float* mem = (const float*)d_in[1];
  const int* topk = (const int*)d_in[2];
  float* out = (float*)d_out;
  int M = in_sizes[1] / DD;                      // 200000
  int nchunk = (M + BM - 1) / BM;                // 6250
  unsigned short* F = (unsigned short*)d_ws;
  float* partial = (float*)((char*)d_ws + (size_t)NPATCH * DD * 2);
  int nb = NBLK;
  if (nb > nchunk) nb = nchunk;

  k_patchnorm<<<NPATCH, 256, 0, stream>>>(pf, F);
  k_main<<<nb, 256, 0, stream>>>(F, mem, partial, M, nchunk);
  k_colmin<<<NPATCH, 256, 0, stream>>>(partial, out, nb);
  k_topk<<<1, 256, 0, stream>>>(out, topk);
}

// Round 2
// 813.017 us; speedup vs baseline: 1.7483x; 1.7483x over previous
//
#include <hip/hip_runtime.h>
#include <hip/hip_bf16.h>

#define DD 768
#define NPATCH 576
#define BM 32            // memory rows staged per chunk
#define NKS 24           // 768 / 32
#define PT_PER_WAVE 9    // 36 patch tiles / 4 waves
#define EPSF 1e-6f
#define NBLK 2048

typedef short bf16x8 __attribute__((ext_vector_type(8)));
typedef float f32x4 __attribute__((ext_vector_type(4)));

__device__ __forceinline__ unsigned short f2bf(float x) {
  __hip_bfloat16 h = __float2bfloat16(x);
  return __builtin_bit_cast(unsigned short, h);
}

// ---------------- kernel 1: normalize patches -> bf16 F ----------------
__global__ __launch_bounds__(256) void k_patchnorm(const float* __restrict__ pf,
                                                   unsigned short* __restrict__ F) {
  int row = blockIdx.x;          // 576
  int t = threadIdx.x;           // 256
  const float* src = pf + row * DD;
  float v0 = src[t], v1 = src[t + 256], v2 = src[t + 512];
  float ss = v0 * v0 + v1 * v1 + v2 * v2;
#pragma unroll
  for (int m = 1; m < 64; m <<= 1) ss += __shfl_xor(ss, m, 64);
  __shared__ float wss[4];
  if ((t & 63) == 0) wss[t >> 6] = ss;
  __syncthreads();
  float tot = wss[0] + wss[1] + wss[2] + wss[3];
  float inv = 1.0f / (sqrtf(tot) + EPSF);
  unsigned short* dst = F + (size_t)row * DD;
  dst[t] = f2bf(v0 * inv);
  dst[t + 256] = f2bf(v1 * inv);
  dst[t + 512] = f2bf(v2 * inv);
}

// ---------------- kernel 2: main MFMA distance/min kernel ----------------
__global__ __launch_bounds__(256, 2) void k_main(const unsigned short* __restrict__ F,
                                                 const float* __restrict__ mem,
                                                 float* __restrict__ partial,
                                                 int M, int nchunk) {
  __shared__ __align__(16) unsigned char mtile[BM * DD * 2];  // 48 KiB bf16 tile
  __shared__ float ssq[BM];
  __shared__ float smin[NPATCH];

  int t = threadIdx.x;
  int w = t >> 6;          // wave 0..3
  int l = t & 63;
  int l15 = l & 15;
  int lhi = l >> 4;

  for (int p = t; p < NPATCH; p += 256) smin[p] = 1e30f;

  for (int chunk = blockIdx.x; chunk < nchunk; chunk += gridDim.x) {
    __syncthreads();  // previous iteration done with mtile/ssq; smin init visible
    // ---- stage: 32 rows x 768 fp32 -> bf16 LDS (swizzled), sumsq per row ----
    {
      int row = t >> 3;              // 0..31
      int part = t & 7;              // 0..7, 96 floats each
      int grow = chunk * BM + row;
      if (grow > M - 1) grow = M - 1;          // clamp (tail safety)
      const float4* src = (const float4*)(mem + (size_t)grow * DD + part * 96);
      char* rowb = (char*)mtile + row * 1536;
      int kb0 = part * 192;
      int sw = (row & 7) << 4;
      float ss = 0.f;
#pragma unroll 4
      for (int i = 0; i < 24; ++i) {
        float4 v = src[i];
        ss += v.x * v.x + v.y * v.y + v.z * v.z + v.w * v.w;
        unsigned int lo = (unsigned int)f2bf(v.x) | ((unsigned int)f2bf(v.y) << 16);
        unsigned int hi = (unsigned int)f2bf(v.z) | ((unsigned int)f2bf(v.w) << 16);
        uint2 u; u.x = lo; u.y = hi;
        *(uint2*)(rowb + ((kb0 + i * 8) ^ sw)) = u;
      }
      ss += __shfl_xor(ss, 1, 64);
      ss += __shfl_xor(ss, 2, 64);
      ss += __shfl_xor(ss, 4, 64);
      if (part == 0) ssq[row] = ss;
    }
    __syncthreads();

    // ---- MFMA: wave w covers patch tiles w*9..w*9+8, full 32 mem rows ----
    f32x4 acc[PT_PER_WAVE][2];
#pragma unroll
    for (int p = 0; p < PT_PER_WAVE; ++p) {
      f32x4 z = {0.f, 0.f, 0.f, 0.f};
      acc[p][0] = z;
      acc[p][1] = z;
    }
    const unsigned short* fb = F + (size_t)(w * PT_PER_WAVE * 16 + l15) * DD + lhi * 8;
    int sw = (l15 & 7) << 4;                       // same for rows l15 and 16+l15
    char* b0base = (char*)mtile + l15 * 1536;
    char* b1base = (char*)mtile + (16 + l15) * 1536;
#pragma unroll 1
    for (int ks = 0; ks < NKS; ++ks) {
      int kb = (ks * 64 + lhi * 16) ^ sw;
      bf16x8 b0 = *(const bf16x8*)(b0base + kb);
      bf16x8 b1 = *(const bf16x8*)(b1base + kb);
      const unsigned short* fk = fb + ks * 32;
#pragma unroll
      for (int p = 0; p < PT_PER_WAVE; ++p) {
        bf16x8 a = *(const bf16x8*)(fk + p * 16 * DD);
        acc[p][0] = __builtin_amdgcn_mfma_f32_16x16x32_bf16(a, b0, acc[p][0], 0, 0, 0);
        acc[p][1] = __builtin_amdgcn_mfma_f32_16x16x32_bf16(a, b1, acc[p][1], 0, 0, 0);
      }
    }

    // ---- epilogue: dist = 1 - dot/(||mem||+eps); min over 32 rows ----
    int mbase = chunk * BM;
    float inv0 = 1.0f / (sqrtf(ssq[l15]) + EPSF);
    float inv1 = 1.0f / (sqrtf(ssq[16 + l15]) + EPSF);
    bool ok0 = (mbase + l15) < M;
    bool ok1 = (mbase + 16 + l15) < M;
#pragma unroll
    for (int p = 0; p < PT_PER_WAVE; ++p) {
      float d[4];
#pragma unroll
      for (int r = 0; r < 4; ++r) {
        float e0 = ok0 ? (1.0f - acc[p][0][r] * inv0) : 1e30f;
        float e1 = ok1 ? (1.0f - acc[p][1][r] * inv1) : 1e30f;
        d[r] = fminf(e0, e1);
      }
#pragma unroll
      for (int mask = 1; mask <= 8; mask <<= 1) {
#pragma unroll
        for (int r = 0; r < 4; ++r) d[r] = fminf(d[r], __shfl_xor(d[r], mask, 64));
      }
      if (l15 == 0) {
        int pbase = (w * PT_PER_WAVE + p) * 16 + lhi * 4;
#pragma unroll
        for (int r = 0; r < 4; ++r) smin[pbase + r] = fminf(smin[pbase + r], d[r]);
      }
    }
  }
  __syncthreads();
  size_t ob = (size_t)blockIdx.x * NPATCH;
  for (int p = t; p < NPATCH; p += 256) partial[ob + p] = smin[p];
}

// ---------------- kernel 3: min over partials -> patch_scores ----------------
__global__ __launch_bounds__(256) void k_colmin(const float* __restrict__ partial,
                                                float* __restrict__ out, int nb) {
  int p = blockIdx.x;   // 576
  int t = threadIdx.x;
  float v = 1e30f;
  for (int b = t; b < nb; b += 256) v = fminf(v, partial[(size_t)b * NPATCH + p]);
#pragma unroll
  for (int m = 1; m < 64; m <<= 1) v = fminf(v, __shfl_xor(v, m, 64));
  __shared__ float wmin[4];
  if ((t & 63) == 0) wmin[t >> 6] = v;
  __syncthreads();
  if (t == 0) out[p] = fminf(fminf(wmin[0], wmin[1]), fminf(wmin[2], wmin[3]));
}

// ---------------- kernel 4: top-k mean -> image score ----------------
__global__ __launch_bounds__(256) void k_topk(float* __restrict__ out,
                                              const int* __restrict__ topk_p) {
  __shared__ float vals[NPATCH];
  __shared__ float wv[4];
  __shared__ int wi[4];
  __shared__ float ssum;
  int t = threadIdx.x;
  for (int p = t; p < NPATCH; p += 256) vals[p] = out[p];
  if (t == 0) ssum = 0.f;
  int k = topk_p[0];
  if (k > NPATCH) k = NPATCH;
  if (k < 1) k = 1;
  __syncthreads();
  for (int it = 0; it < k; ++it) {
    float bv = -1e30f;
    int bi = 0;
    for (int p = t; p < NPATCH; p += 256) {
      float x = vals[p];
      if (x > bv) { bv = x; bi = p; }
    }
#pragma unroll
    for (int m = 1; m < 64; m <<= 1) {
      float ov = __shfl_xor(bv, m, 64);
      int oi = __shfl_xor(bi, m, 64);
      if (ov > bv || (ov == bv && oi < bi)) { bv = ov; bi = oi; }
    }
    if ((t & 63) == 0) { wv[t >> 6] = bv; wi[t >> 6] = bi; }
    __syncthreads();
    if (t == 0) {
      float fbv = wv[0]; int fbi = wi[0];
      for (int q = 1; q < 4; ++q)
        if (wv[q] > fbv || (wv[q] == fbv && wi[q] < fbi)) { fbv = wv[q]; fbi = wi[q]; }
      ssum += fbv;
      vals[fbi] = -1e30f;
    }
    __syncthreads();
  }
  if (t == 0) out[NPATCH] = ssum / (float)k;
}

extern "C" void kernel_launch(void* const* d_in, const int* in_sizes, int n_in,
                              void* d_out, int out_size, void* d_ws, size_t ws_size,
                              hipStream_t stream) {
  const float* pf = (const float*)d_in[0];
  const float* mem = (const float*)d_in[1];
  const int* topk = (const int*)d_in[2];
  float* out = (float*)d_out;
  int M = in_sizes[1] / DD;                      // 200000
  int nchunk = (M + BM - 1) / BM;                // 6250
  unsigned short* F = (unsigned short*)d_ws;
  float* partial = (float*)((char*)d_ws + (size_t)NPATCH * DD * 2);
  int nb = NBLK;
  if (nb > nchunk) nb = nchunk;

  k_patchnorm<<<NPATCH, 256, 0, stream>>>(pf, F);
  k_main<<<nb, 256, 0, stream>>>(F, mem, partial, M, nchunk);
  k_colmin<<<NPATCH, 256, 0, stream>>>(partial, out, nb);
  k_topk<<<1, 256, 0, stream>>>(out, topk);
}

// Round 3
// 595.226 us; speedup vs baseline: 2.3880x; 1.3659x over previous
//
#include <hip/hip_runtime.h>
#include <hip/hip_bf16.h>

#define DD 768
#define NPATCH 576
#define NPAD 640          // padded patches (40 tiles of 16)
#define BM 128            // mem rows per block-chunk
#define NSLAB 24          // K slabs of 32
#define EPSF 1e-6f

typedef short bf16x8 __attribute__((ext_vector_type(8)));
typedef float f32x4 __attribute__((ext_vector_type(4)));

__device__ __forceinline__ unsigned short f2bf(float x) {
  __hip_bfloat16 h = __float2bfloat16(x);
  return __builtin_bit_cast(unsigned short, h);
}

// ---------------- kernel 1: patch row norms ----------------
__global__ __launch_bounds__(256) void k_norm(const float* __restrict__ pf,
                                              float* __restrict__ invn) {
  int row = blockIdx.x;          // 576
  int t = threadIdx.x;
  const float* src = pf + (size_t)row * DD;
  float v0 = src[t], v1 = src[t + 256], v2 = src[t + 512];
  float ss = v0 * v0 + v1 * v1 + v2 * v2;
#pragma unroll
  for (int m = 1; m < 64; m <<= 1) ss += __shfl_xor(ss, m, 64);
  __shared__ float wss[4];
  if ((t & 63) == 0) wss[t >> 6] = ss;
  __syncthreads();
  if (t == 0) {
    float tot = wss[0] + wss[1] + wss[2] + wss[3];
    invn[row] = 1.0f / (sqrtf(tot) + EPSF);
  }
}

// ---------------- kernel 2: pack F into slab-fragment layout ----------------
// Fws[ks][pt][slot][8] bf16: patch = pt*16 + (slot&15), k = ks*32 + (slot>>4)*8 + j
__global__ __launch_bounds__(256) void k_pack(const float* __restrict__ pf,
                                              const float* __restrict__ invn,
                                              unsigned short* __restrict__ Fws) {
  int bid = blockIdx.x;          // 960 = 24 ks * 40 pt
  int ks = bid / 40, pt = bid % 40;
  int t = threadIdx.x;
  int i = t * 2;                 // short index in region [0,512)
  int s = i >> 3, j = i & 7;
  int p = pt * 16 + (s & 15);
  int k = ks * 32 + (s >> 4) * 8 + j;
  unsigned int outw = 0;
  if (p < NPATCH) {
    float sc = invn[p];
    float a0 = pf[(size_t)p * DD + k] * sc;
    float a1 = pf[(size_t)p * DD + k + 1] * sc;
    outw = (unsigned int)f2bf(a0) | ((unsigned int)f2bf(a1) << 16);
  }
  ((unsigned int*)Fws)[(size_t)bid * 256 + t] = outw;
}

// ---------------- kernel 3: main MFMA kernel ----------------
// 512 threads = 8 waves: pw = w&3 (10 patch-tiles each), rw = w>>2 (64 rows each)
__global__ __launch_bounds__(512, 2) void k_main(const unsigned short* __restrict__ Fws,
                                                 const float* __restrict__ mem,
                                                 float* __restrict__ partial,
                                                 int M, int nchunk) {
  __shared__ __align__(16) unsigned short As[2][40 * 512];   // 2 x 40KB
  __shared__ __align__(16) unsigned short Bs[2][8 * 512];    // 2 x 8KB
  __shared__ float ssq[BM];
  __shared__ float smin[2][NPAD];

  int t = threadIdx.x;
  int w = t >> 6, l = t & 63, l15 = l & 15, lhi = l >> 4;
  int pw = w & 3, rw = w >> 2;

  for (int i = t; i < 2 * NPAD; i += 512) ((float*)smin)[i] = 1e30f;

  // B-staging per-thread constants: entry t -> (rt, lhi_b, l15_b)
  int brow_local = (t >> 6) * 16 + (t & 15);
  int bkg = ((t >> 4) & 3) * 8;

#pragma unroll 1
  for (int chunk = blockIdx.x; chunk < nchunk; chunk += gridDim.x) {
    if (t < BM) ssq[t] = 0.f;
    float ssr = 0.f;
    int growb = chunk * BM + brow_local;
    if (growb > M - 1) growb = M - 1;
    const float* gbase = mem + (size_t)growb * DD + bkg;

    // ---- prologue: stage slab 0 into buf 0 ----
    {
      float4 v0 = *(const float4*)(gbase);
      float4 v1 = *(const float4*)(gbase + 4);
      uint4 av[5];
      const uint4* asrc = (const uint4*)Fws;
#pragma unroll
      for (int i = 0; i < 5; ++i) av[i] = asrc[t + i * 512];
#pragma unroll
      for (int i = 0; i < 5; ++i) ((uint4*)As[0])[t + i * 512] = av[i];
      ssr += v0.x * v0.x + v0.y * v0.y + v0.z * v0.z + v0.w * v0.w +
             v1.x * v1.x + v1.y * v1.y + v1.z * v1.z + v1.w * v1.w;
      uint4 bw;
      bw.x = (unsigned int)f2bf(v0.x) | ((unsigned int)f2bf(v0.y) << 16);
      bw.y = (unsigned int)f2bf(v0.z) | ((unsigned int)f2bf(v0.w) << 16);
      bw.z = (unsigned int)f2bf(v1.x) | ((unsigned int)f2bf(v1.y) << 16);
      bw.w = (unsigned int)f2bf(v1.z) | ((unsigned int)f2bf(v1.w) << 16);
      ((uint4*)Bs[0])[t] = bw;
    }
    __syncthreads();

    f32x4 acc[10][4];
#pragma unroll
    for (int p = 0; p < 10; ++p)
#pragma unroll
      for (int r = 0; r < 4; ++r) {
        f32x4 z = {0.f, 0.f, 0.f, 0.f};
        acc[p][r] = z;
      }

#pragma unroll 1
    for (int ks = 0; ks < NSLAB; ++ks) {
      int cur = ks & 1, nxt = cur ^ 1;
      bool st = ks < NSLAB - 1;
      float4 v0, v1;
      uint4 av[5];
      if (st) {
        // issue B (HBM, long latency) first, then A (L2-hot)
        const float* gr = gbase + (ks + 1) * 32;
        v0 = *(const float4*)gr;
        v1 = *(const float4*)(gr + 4);
        const uint4* asrc = (const uint4*)(Fws + (size_t)(ks + 1) * 20480);
#pragma unroll
        for (int i = 0; i < 5; ++i) av[i] = asrc[t + i * 512];
      }
      // ---- compute on cur ----
      const unsigned short* AsC = As[cur];
      const unsigned short* BsC = Bs[cur];
      int soff = (lhi * 16 + l15) * 8;
      bf16x8 b[4];
#pragma unroll
      for (int r = 0; r < 4; ++r)
        b[r] = *(const bf16x8*)(BsC + (rw * 4 + r) * 512 + soff);
#pragma unroll
      for (int p = 0; p < 10; ++p) {
        bf16x8 a = *(const bf16x8*)(AsC + (pw * 10 + p) * 512 + soff);
#pragma unroll
        for (int r = 0; r < 4; ++r)
          acc[p][r] = __builtin_amdgcn_mfma_f32_16x16x32_bf16(a, b[r], acc[p][r], 0, 0, 0);
      }
      // ---- write staged data ----
      if (st) {
#pragma unroll
        for (int i = 0; i < 5; ++i) ((uint4*)As[nxt])[t + i * 512] = av[i];
        ssr += v0.x * v0.x + v0.y * v0.y + v0.z * v0.z + v0.w * v0.w +
               v1.x * v1.x + v1.y * v1.y + v1.z * v1.z + v1.w * v1.w;
        uint4 bw;
        bw.x = (unsigned int)f2bf(v0.x) | ((unsigned int)f2bf(v0.y) << 16);
        bw.y = (unsigned int)f2bf(v0.z) | ((unsigned int)f2bf(v0.w) << 16);
        bw.z = (unsigned int)f2bf(v1.x) | ((unsigned int)f2bf(v1.y) << 16);
        bw.w = (unsigned int)f2bf(v1.z) | ((unsigned int)f2bf(v1.w) << 16);
        ((uint4*)Bs[nxt])[t] = bw;
        if (ks == NSLAB - 2) atomicAdd(&ssq[brow_local], ssr);
      }
      __syncthreads();
    }

    // ---- epilogue: dist + min over this chunk's 128 rows ----
    float inv[4];
    bool ok[4];
#pragma unroll
    for (int r = 0; r < 4; ++r) {
      int rl = rw * 64 + r * 16 + l15;
      inv[r] = 1.0f / (sqrtf(ssq[rl]) + EPSF);
      ok[r] = (chunk * BM + rl) < M;
    }
#pragma unroll
    for (int p = 0; p < 10; ++p) {
#pragma unroll
      for (int q = 0; q < 4; ++q) {
        float d = 1e30f;
#pragma unroll
        for (int r = 0; r < 4; ++r) {
          float e = ok[r] ? (1.0f - acc[p][r][q] * inv[r]) : 1e30f;
          d = fminf(d, e);
        }
        d = fminf(d, __shfl_xor(d, 1, 64));
        d = fminf(d, __shfl_xor(d, 2, 64));
        d = fminf(d, __shfl_xor(d, 4, 64));
        d = fminf(d, __shfl_xor(d, 8, 64));
        if (l15 == 0) {
          int patch = (pw * 10 + p) * 16 + lhi * 4 + q;
          smin[rw][patch] = fminf(smin[rw][patch], d);
        }
      }
    }
    __syncthreads();   // smin/ssq settled before next chunk reuses them
  }

  for (int p = t; p < NPATCH; p += 512)
    partial[(size_t)blockIdx.x * NPATCH + p] = fminf(smin[0][p], smin[1][p]);
}

// ---------------- kernel 4: min over partials -> patch_scores ----------------
__global__ __launch_bounds__(256) void k_colmin(const float* __restrict__ partial,
                                                float* __restrict__ out, int nb) {
  int p = blockIdx.x;   // 576
  int t = threadIdx.x;
  float v = 1e30f;
  for (int b = t; b < nb; b += 256) v = fminf(v, partial[(size_t)b * NPATCH + p]);
#pragma unroll
  for (int m = 1; m < 64; m <<= 1) v = fminf(v, __shfl_xor(v, m, 64));
  __shared__ float wmin[4];
  if ((t & 63) == 0) wmin[t >> 6] = v;
  __syncthreads();
  if (t == 0) out[p] = fminf(fminf(wmin[0], wmin[1]), fminf(wmin[2], wmin[3]));
}

// ---------------- kernel 5: top-k mean -> image score ----------------
__global__ __launch_bounds__(256) void k_topk(float* __restrict__ out,
                                              const int* __restrict__ topk_p) {
  __shared__ float vals[NPATCH];
  __shared__ float wv[4];
  __shared__ int wi[4];
  __shared__ float ssum;
  int t = threadIdx.x;
  for (int p = t; p < NPATCH; p += 256) vals[p] = out[p];
  if (t == 0) ssum = 0.f;
  int k = topk_p[0];
  if (k > NPATCH) k = NPATCH;
  if (k < 1) k = 1;
  __syncthreads();
  for (int it = 0; it < k; ++it) {
    float bv = -1e30f;
    int bi = 0;
    for (int p = t; p < NPATCH; p += 256) {
      float x = vals[p];
      if (x > bv) { bv = x; bi = p; }
    }
#pragma unroll
    for (int m = 1; m < 64; m <<= 1) {
      float ov = __shfl_xor(bv, m, 64);
      int oi = __shfl_xor(bi, m, 64);
      if (ov > bv || (ov == bv && oi < bi)) { bv = ov; bi = oi; }
    }
    if ((t & 63) == 0) { wv[t >> 6] = bv; wi[t >> 6] = bi; }
    __syncthreads();
    if (t == 0) {
      float fbv = wv[0]; int fbi = wi[0];
      for (int q = 1; q < 4; ++q)
        if (wv[q] > fbv || (wv[q] == fbv && wi[q] < fbi)) { fbv = wv[q]; fbi = wi[q]; }
      ssum += fbv;
      vals[fbi] = -1e30f;
    }
    __syncthreads();
  }
  if (t == 0) out[NPATCH] = ssum / (float)k;
}

extern "C" void kernel_launch(void* const* d_in, const int* in_sizes, int n_in,
                              void* d_out, int out_size, void* d_ws, size_t ws_size,
                              hipStream_t stream) {
  const float* pf = (const float*)d_in[0];
  const float* mem = (const float*)d_in[1];
  const int* topk = (const int*)d_in[2];
  float* out = (float*)d_out;
  int M = in_sizes[1] / DD;                      // 200000
  int nchunk = (M + BM - 1) / BM;                // 1563

  // ws layout: Fws (24*40*512 shorts = 983040B) | invn (640*4) | partial (256*576*4)
  unsigned short* Fws = (unsigned short*)d_ws;
  float* invn = (float*)((char*)d_ws + 983040);
  float* partial = (float*)((char*)d_ws + 983040 + 2560);

  int nblk = 256;
  if (nblk > nchunk) nblk = nchunk;

  k_norm<<<NPATCH, 256, 0, stream>>>(pf, invn);
  k_pack<<<960, 256, 0, stream>>>(pf, invn, Fws);
  k_main<<<nblk, 512, 0, stream>>>(Fws, mem, partial, M, nchunk);
  k_colmin<<<NPATCH, 256, 0, stream>>>(partial, out, nblk);
  k_topk<<<1, 256, 0, stream>>>(out, topk);
}